// Round 8
// baseline (261.424 us; speedup 1.0000x reference)
//
#include <hip/hip_runtime.h>
#include <math.h>

// ---------------- workspace layout (float offsets) ----------------
#define WS_E0   0       // E_s[19]
#define WS_E1   19      // E_t[19]
#define WS_G0   64      // G_s[361] (i<=j)
#define WS_G1   448     // G_t[361]
#define WS_Z    1152    // row sumexp [304]
#define WS_WBF  2048    // conv_w as bf16 [768*128] -> 49152 float slots

typedef __bf16 bf16x8 __attribute__((ext_vector_type(8)));
typedef float  f32x4  __attribute__((ext_vector_type(4)));
typedef const __attribute__((address_space(1))) unsigned int guint;
typedef       __attribute__((address_space(3))) unsigned int luint;

// ---------------- init: zero accumulators + convert W to bf16 ----------------
__global__ void k_init(const float* __restrict__ conv_w, float* __restrict__ ws,
                       float* __restrict__ out) {
    const int bx = blockIdx.x, tid = threadIdx.x;
    if (bx < 96) {
        __bf16* Wb = (__bf16*)(ws + WS_WBF);
        #pragma unroll
        for (int j = 0; j < 4; j++) {
            int idx = bx * 1024 + j * 256 + tid;
            Wb[idx] = (__bf16)conv_w[idx];
        }
    } else {
        for (int k = tid; k < 2048; k += 256) ws[k] = 0.f;
        if (tid < 2) out[tid] = 0.f;
    }
}

// ---------------- bilinear sample of t_logit row (65x65 -> 129x129) ----------------
__device__ __forceinline__ float t_resized(const float* __restrict__ Trow, int k) {
    int y = k / 129, x = k - y * 129;
    int y0 = y >> 1, x0 = x >> 1;
    int y1 = y0 + (y & 1), x1 = x0 + (x & 1);
    float fy = 0.5f * (float)(y & 1), fx = 0.5f * (float)(x & 1);
    float v00 = Trow[y0 * 65 + x0], v01 = Trow[y0 * 65 + x1];
    float v10 = Trow[y1 * 65 + x0], v11 = Trow[y1 * 65 + x1];
    float r0 = v00 + fx * (v01 - v00);
    float r1 = v10 + fx * (v11 - v10);
    return r0 + fy * (r1 - r0);
}

// ---------------- main: pi (0..1055) + rowstats (1056..1359) + corner (1360..1367) --
// pi block = (b, strip of 32 px), ALL 768 channels as 12 macro-unrolled chunks of 64.
//  - LDS 33.5KB -> 4 blocks/CU (waves_per_eu(4,4), VGPR budget 128)
//  - xs persistent [32][140] bf16; B-frags re-read per chunk (short-lived temps)
//  - A-frags: two NAMED sets alternated at literal c (spill-proof)
//  - t TRIPLE-buffered, 8KB/chunk (2KB/wave), 2 global_load_lds per chunk per wave;
//    t(c+2) issued after compute(c) -> ~2 compute phases of flight
//  - t rows stored rotated by 4 px per row (pre-rotated global src), un-rotated
//    at read -> 2-way LDS banks (free)
//  - waits (t=2 ops, A=5 ops, pinned order): steps 0..10 vmcnt(7), step 11 vmcnt(5)
__global__ __launch_bounds__(256)
__attribute__((amdgpu_waves_per_eu(4, 4)))
void k_main(const float* __restrict__ s_out, const float* __restrict__ t_out,
            const float* __restrict__ conv_w, const float* __restrict__ bias,
            const float* __restrict__ s_logit, const float* __restrict__ t_logit,
            float* __restrict__ ws, float* __restrict__ out) {
    __shared__ __align__(16) char lds[33536];   // xs 8960 + 3 t-bufs 24576
    const int tid = threadIdx.x;
    const int bx  = blockIdx.x;

    if (bx < 1056) {
        // ================= pi role =================
        const int b     = bx / 132;
        const int strip = bx - b * 132;
        const int px0   = strip * 32;

        const int l = tid & 63, g = tid >> 6, q = l >> 4, n = l & 15;
        const int og  = g * 16;                   // wave's 16 rows within each 64-chunk
        const int nmq = n - q * 16;               // read un-rotation base

        // ---- t source addressing: row-local rotation by 4 px per row ----
        const float* base_t = t_out + (size_t)(b * 768 + og) * 4225;
        const int px_local = (((l & 7) * 4) + 4 * (l >> 3)) & 31;
        int off[2];
        #pragma unroll
        for (int j = 0; j < 2; j++)
            off[j] = (j * 8 + (l >> 3)) * 4225 + px0 + px_local;

        auto issue_t = [&](int cc) {              // cc always literal; buf = cc%3
            char* lb = lds + 8960 + (cc % 3) * 8192 + g * 2048;
            const float* gb = base_t + (size_t)cc * 64 * 4225;
            #pragma unroll
            for (int j = 0; j < 2; j++)
                __builtin_amdgcn_global_load_lds((guint*)(gb + off[j]),
                                                 (luint*)(lb + j * 1024), 16, 0, 0);
        };

        issue_t(0);
        issue_t(1);           // resize below hides both chunks' HBM latency

        __bf16* xs = (__bf16*)lds;               // 32 px x 140 c bf16 (padded stride)

        // ---- bilinear resize 33x33 -> 65x65, 32-px strip, once per strip ----
        {
            const float* Sb = s_out + b * 128 * 1089;
            #pragma unroll
            for (int ii = 0; ii < 16; ii++) {
                int id2 = tid + ii * 256;
                int c = id2 >> 5, px = id2 & 31;
                int hw = px0 + px;
                int h = hw / 65, w = hw - h * 65;
                int y0 = h >> 1, x0 = w >> 1;
                int y1 = y0 + (h & 1), x1 = x0 + (w & 1);
                float wy = 0.5f * (float)(h & 1), wx = 0.5f * (float)(w & 1);
                const float* Sc = Sb + c * 1089;
                float v00 = Sc[y0 * 33 + x0], v01 = Sc[y0 * 33 + x1];
                float v10 = Sc[y1 * 33 + x0], v11 = Sc[y1 * 33 + x1];
                float r0 = v00 + wx * (v01 - v00);
                float r1 = v10 + wx * (v11 - v10);
                xs[px * 140 + c] = (__bf16)(r0 + wy * (r1 - r0));
            }
        }
        // barrier WITHOUT vmcnt drain (keep t0/t1 in flight); xs stable hereafter
        asm volatile("s_waitcnt lgkmcnt(0)" ::: "memory");
        __builtin_amdgcn_s_barrier();
        __builtin_amdgcn_sched_barrier(0);

        const __bf16* Wbf = (const __bf16*)(ws + WS_WBF);
        bf16x8 aA0, aA1, aA2, aA3, aB0, aB1, aB2, aB3;
        f32x4  bqA, bqB;

#define LOAD_A(cc, A0_, A1_, A2_, A3_, BQ_) do {                                          \
        const __bf16* Wr_ = Wbf + (size_t)((cc) * 64 + og + n) * 128 + q * 8;             \
        A0_ = *(const bf16x8*)(Wr_);       A1_ = *(const bf16x8*)(Wr_ + 32);              \
        A2_ = *(const bf16x8*)(Wr_ + 64);  A3_ = *(const bf16x8*)(Wr_ + 96);              \
        BQ_ = *(const f32x4*)&bias[(cc) * 64 + og + q * 4];                               \
    } while (0)

        LOAD_A(0, aA0, aA1, aA2, aA3, bqA);

        float Zt[2], St[2], Dd[2], Zs[2];
        #pragma unroll
        for (int pt = 0; pt < 2; pt++) { Zt[pt] = 0.f; St[pt] = 0.f; Dd[pt] = 0.f; Zs[pt] = 0.f; }

#define PI_STEP(c, NW, A0_, A1_, A2_, A3_, BQ_, NA0_, NA1_, NA2_, NA3_, NBQ_)             \
        asm volatile("s_waitcnt vmcnt(" #NW ")" ::: "memory");                            \
        if ((c) < 11) LOAD_A((c) + 1, NA0_, NA1_, NA2_, NA3_, NBQ_);                      \
        {                                                                                 \
            const float* tw_ = (const float*)(lds + 8960 + ((c) % 3) * 8192 + g * 2048);  \
            _Pragma("unroll")                                                             \
            for (int pt = 0; pt < 2; pt++) {                                              \
                const __bf16* bx_ = &xs[(pt * 16 + n) * 140 + q * 8];                     \
                bf16x8 b0_ = *(const bf16x8*)(bx_);                                       \
                bf16x8 b1_ = *(const bf16x8*)(bx_ + 32);                                  \
                bf16x8 b2_ = *(const bf16x8*)(bx_ + 64);                                  \
                bf16x8 b3_ = *(const bf16x8*)(bx_ + 96);                                  \
                f32x4 a0_ = {0.f, 0.f, 0.f, 0.f};                                         \
                a0_ = __builtin_amdgcn_mfma_f32_16x16x32_bf16(A0_, b0_, a0_, 0, 0, 0);    \
                a0_ = __builtin_amdgcn_mfma_f32_16x16x32_bf16(A1_, b1_, a0_, 0, 0, 0);    \
                a0_ = __builtin_amdgcn_mfma_f32_16x16x32_bf16(A2_, b2_, a0_, 0, 0, 0);    \
                a0_ = __builtin_amdgcn_mfma_f32_16x16x32_bf16(A3_, b3_, a0_, 0, 0, 0);    \
                _Pragma("unroll")                                                         \
                for (int r = 0; r < 4; r++) {                                             \
                    float tv  = tw_[(q * 4 + r) * 32 + ((pt * 16 + nmq - 4 * r) & 31)];   \
                    float s1v = a0_[r] + BQ_[r];                                          \
                    float e   = __expf(tv);                                               \
                    Zt[pt] += e;                                                          \
                    St[pt]  = fmaf(e, tv,  St[pt]);                                       \
                    Dd[pt]  = fmaf(e, s1v, Dd[pt]);                                       \
                    Zs[pt] += __expf(s1v);                                                \
                }                                                                         \
            }                                                                             \
        }                                                                                 \
        if ((c) <= 9) issue_t((c) + 2);

        PI_STEP(0,  7, aA0, aA1, aA2, aA3, bqA, aB0, aB1, aB2, aB3, bqB)
        PI_STEP(1,  7, aB0, aB1, aB2, aB3, bqB, aA0, aA1, aA2, aA3, bqA)
        PI_STEP(2,  7, aA0, aA1, aA2, aA3, bqA, aB0, aB1, aB2, aB3, bqB)
        PI_STEP(3,  7, aB0, aB1, aB2, aB3, bqB, aA0, aA1, aA2, aA3, bqA)
        PI_STEP(4,  7, aA0, aA1, aA2, aA3, bqA, aB0, aB1, aB2, aB3, bqB)
        PI_STEP(5,  7, aB0, aB1, aB2, aB3, bqB, aA0, aA1, aA2, aA3, bqA)
        PI_STEP(6,  7, aA0, aA1, aA2, aA3, bqA, aB0, aB1, aB2, aB3, bqB)
        PI_STEP(7,  7, aB0, aB1, aB2, aB3, bqB, aA0, aA1, aA2, aA3, bqA)
        PI_STEP(8,  7, aA0, aA1, aA2, aA3, bqA, aB0, aB1, aB2, aB3, bqB)
        PI_STEP(9,  7, aB0, aB1, aB2, aB3, bqB, aA0, aA1, aA2, aA3, bqA)
        PI_STEP(10, 7, aA0, aA1, aA2, aA3, bqA, aB0, aB1, aB2, aB3, bqB)
        PI_STEP(11, 5, aB0, aB1, aB2, aB3, bqB, aA0, aA1, aA2, aA3, bqA)
#undef PI_STEP
#undef LOAD_A

        // ---- merge 16 partitions (4 waves x 4 quads) per pixel, once ----
        __syncthreads();                          // drains all VMEM too
        float* scr = (float*)lds;                 // xs region, dead now (32*68*4=8704)
        {
            int p = g * 4 + q;
            #pragma unroll
            for (int pt = 0; pt < 2; pt++) {
                f32x4 v = {Zt[pt], St[pt], Dd[pt], Zs[pt]};
                *(f32x4*)&scr[(pt * 16 + n) * 68 + p * 4] = v;
            }
        }
        __syncthreads();
        if (tid < 32) {
            float Z = 0.f, S = 0.f, D = 0.f, Z2 = 0.f;
            #pragma unroll
            for (int p = 0; p < 16; p++) {
                f32x4 v = *(const f32x4*)&scr[tid * 68 + p * 4];
                Z += v[0]; S += v[1]; D += v[2]; Z2 += v[3];
            }
            float contrib = (S - D) / Z - logf(Z) + logf(Z2);
            #pragma unroll
            for (int o = 16; o > 0; o >>= 1) contrib += __shfl_down(contrib, o);
            if (tid == 0) atomicAdd(out, contrib * (1.0f / 25958400.0f));
        }
    } else if (bx < 1360) {
        // ================= rowstats role =================
        float* red = (float*)lds;
        int row  = bx - 1056;
        int side = (row >= 152) ? 1 : 0;
        int r    = side ? row - 152 : row;
        const float* src = side ? (t_logit + r * 4225) : (s_logit + r * 16641);

        float z = 0.f, s = 0.f;
        #pragma unroll 4
        for (int k = tid; k < 16641; k += 256) {
            float v = side ? t_resized(src, k) : src[k];
            float e = __expf(v);
            z += e;
            s = fmaf(e, v, s);
        }
        for (int off = 32; off > 0; off >>= 1) { z += __shfl_down(z, off); s += __shfl_down(s, off); }
        if ((tid & 63) == 0) { red[tid >> 6] = z; red[4 + (tid >> 6)] = s; }
        __syncthreads();
        if (tid == 0) {
            float Z = red[0] + red[1] + red[2] + red[3];
            float S = red[4] + red[5] + red[6] + red[7];
            ws[WS_Z + row] = Z;
            atomicAdd(&ws[(side ? WS_E1 : WS_E0) + (r % 19)], S / Z - logf(Z));
        }
    } else {
        // ================= corner pixel (px 4224) role, one block per b ==========
        float* xc  = (float*)lds;          // 128
        float* red = (float*)lds + 128;    // 16
        const int b = bx - 1360;
        if (tid < 128) xc[tid] = s_out[((size_t)b * 128 + tid) * 1089 + 1088];
        __syncthreads();
        float z = 0.f, s = 0.f, d = 0.f, z2 = 0.f;
        #pragma unroll
        for (int rep = 0; rep < 3; rep++) {
            int o = tid + rep * 256;
            const float* Wr = conv_w + (size_t)o * 128;
            float s1 = bias[o];
            for (int cc = 0; cc < 128; cc++) s1 = fmaf(Wr[cc], xc[cc], s1);
            float tv = t_out[((size_t)(b * 768 + o)) * 4225 + 4224];
            float e  = __expf(tv);
            z += e; s = fmaf(e, tv, s); d = fmaf(e, s1, d); z2 += __expf(s1);
        }
        for (int off = 32; off > 0; off >>= 1) {
            z += __shfl_down(z, off); s += __shfl_down(s, off);
            d += __shfl_down(d, off); z2 += __shfl_down(z2, off);
        }
        if ((tid & 63) == 0) {
            int wv = tid >> 6;
            red[wv] = z; red[4 + wv] = s; red[8 + wv] = d; red[12 + wv] = z2;
        }
        __syncthreads();
        if (tid == 0) {
            float Z = red[0] + red[1] + red[2] + red[3];
            float S = red[4] + red[5] + red[6] + red[7];
            float D = red[8] + red[9] + red[10] + red[11];
            float Z2 = red[12] + red[13] + red[14] + red[15];
            float contrib = (S - D) / Z - logf(Z) + logf(Z2);
            atomicAdd(out, contrib * (1.0f / 25958400.0f));
        }
    }
}

// ---------------- mid: Gram (528 blocks, max parallelism) ----------------
#define KT 512
#define KP 516
__global__ void k_mid(const float* __restrict__ s_logit, const float* __restrict__ t_logit,
                      float* __restrict__ ws, float* __restrict__ out) {
    __shared__ __align__(16) char lds[39296];
    const int tid = threadIdx.x;
    const int bx  = blockIdx.x;

    float* pbuf  = (float*)lds;
    float* rowiz = (float*)(lds + 39216);
    int side = (bx >= 264) ? 1 : 0;
    int rm   = side ? bx - 264 : bx;
    int b = rm / 33, kt = rm - b * 33;
    int k0 = kt * KT;

    if (tid < 19) rowiz[tid] = 1.0f / ws[WS_Z + side * 152 + b * 19 + tid];
    __syncthreads();

    for (int i = 0; i < 19; i++) {
        const float* src = side ? (t_logit + (size_t)(b * 19 + i) * 4225)
                                : (s_logit + (size_t)(b * 19 + i) * 16641);
        float iz = rowiz[i];
        #pragma unroll
        for (int kl = tid; kl < KT; kl += 256) {
            int k = k0 + kl;
            float p = 0.f;
            if (k < 16641) {
                float v = side ? t_resized(src, k) : src[k];
                p = __expf(v) * iz;
            }
            pbuf[i * KP + kl] = p;
        }
    }
    __syncthreads();

    if (tid < 190) {
        int t = tid, i = 0;
        while (t >= 19 - i) { t -= 19 - i; i++; }
        int j = i + t;
        const float* pi_ = &pbuf[i * KP];
        const float* pj_ = &pbuf[j * KP];
        float g0 = 0.f, g1 = 0.f, g2 = 0.f, g3 = 0.f;
        #pragma unroll 2
        for (int kl = 0; kl < KT; kl += 16) {
            float4 a0 = *(const float4*)&pi_[kl];      float4 c0 = *(const float4*)&pj_[kl];
            float4 a1 = *(const float4*)&pi_[kl + 4];  float4 c1 = *(const float4*)&pj_[kl + 4];
            float4 a2 = *(const float4*)&pi_[kl + 8];  float4 c2 = *(const float4*)&pj_[kl + 8];
            float4 a3 = *(const float4*)&pi_[kl + 12]; float4 c3 = *(const float4*)&pj_[kl + 12];
            g0 = fmaf(a0.x, c0.x, g0); g0 = fmaf(a0.y, c0.y, g0);
            g0 = fmaf(a0.z, c0.z, g0); g0 = fmaf(a0.w, c0.w, g0);
            g1 = fmaf(a1.x, c1.x, g1); g1 = fmaf(a1.y, c1.y, g1);
            g1 = fmaf(a1.z, c1.z, g1); g1 = fmaf(a1.w, c1.w, g1);
            g2 = fmaf(a2.x, c2.x, g2); g2 = fmaf(a2.y, c2.y, g2);
            g2 = fmaf(a2.z, c2.z, g2); g2 = fmaf(a2.w, c2.w, g2);
            g3 = fmaf(a3.x, c3.x, g3); g3 = fmaf(a3.y, c3.y, g3);
            g3 = fmaf(a3.z, c3.z, g3); g3 = fmaf(a3.w, c3.w, g3);
        }
        atomicAdd(&ws[(side ? WS_G1 : WS_G0) + i * 19 + j], (g0 + g1) + (g2 + g3));
    }
}

// ---------------- finalize lo_loss (1 block, 384 threads) ----------------
__global__ void k_final(const float* __restrict__ ws, float* __restrict__ out) {
    __shared__ float Ms[361], Mt[361], ns[19], nt[19];
    __shared__ float red[8];
    int tid = threadIdx.x;
    if (tid < 361) {
        int i = tid / 19, j = tid - i * 19;
        int lo = min(i, j), hi = max(i, j);
        Ms[tid] = (ws[WS_E0 + hi] - ws[WS_G0 + lo * 19 + hi]) * 0.125f;
        Mt[tid] = (ws[WS_E1 + hi] - ws[WS_G1 + lo * 19 + hi]) * 0.125f;
    }
    __syncthreads();
    if (tid < 19) {
        float as = 0.f, at = 0.f;
        for (int j = 0; j < 19; j++) {
            as = fmaf(Ms[tid * 19 + j], Ms[tid * 19 + j], as);
            at = fmaf(Mt[tid * 19 + j], Mt[tid * 19 + j], at);
        }
        ns[tid] = fmaxf(sqrtf(as), 1e-12f);
        nt[tid] = fmaxf(sqrtf(at), 1e-12f);
    }
    __syncthreads();
    float d = 0.f;
    if (tid < 361) {
        int i = tid / 19;
        float v = Ms[tid] / ns[i] - Mt[tid] / nt[i];
        d = v * v;
    }
    for (int off = 32; off > 0; off >>= 1) d += __shfl_down(d, off);
    if ((tid & 63) == 0) red[tid >> 6] = d;
    __syncthreads();
    if (tid == 0) out[1] = red[0] + red[1] + red[2] + red[3] + red[4] + red[5];
}

extern "C" void kernel_launch(void* const* d_in, const int* in_sizes, int n_in,
                              void* d_out, int out_size, void* d_ws, size_t ws_size,
                              hipStream_t stream) {
    const float* s_out   = (const float*)d_in[0];
    const float* t_out   = (const float*)d_in[1];
    const float* t_logit = (const float*)d_in[2];
    const float* s_logit = (const float*)d_in[3];
    const float* conv_w  = (const float*)d_in[4];
    const float* conv_b  = (const float*)d_in[5];
    float* out = (float*)d_out;
    float* ws  = (float*)d_ws;

    k_init<<<dim3(97), dim3(256), 0, stream>>>(conv_w, ws, out);
    k_main<<<dim3(1368), dim3(256), 0, stream>>>(s_out, t_out, conv_w, conv_b,
                                                 s_logit, t_logit, ws, out);
    k_mid<<<dim3(528), dim3(256), 0, stream>>>(s_logit, t_logit, ws, out);
    k_final<<<dim3(1), dim3(384), 0, stream>>>(ws, out);
}

// Round 9
// 234.843 us; speedup vs baseline: 1.1132x; 1.1132x over previous
//
#include <hip/hip_runtime.h>
#include <math.h>

// ---------------- workspace layout (float offsets) ----------------
#define WS_E0   0       // E_s[19]
#define WS_E1   19      // E_t[19]
#define WS_G0   64      // G_s[361] (i<=j)
#define WS_G1   448     // G_t[361]
#define WS_Z    1152    // row sumexp [304]
#define WS_WBF  2048    // conv_w as bf16 [768*128] -> 49152 float slots
#define WS_PART 51200   // quarter partials [4][8][4224][4] f32 = 540672 floats

typedef __bf16 bf16x8 __attribute__((ext_vector_type(8)));
typedef float  f32x4  __attribute__((ext_vector_type(4)));
typedef const __attribute__((address_space(1))) unsigned int guint;
typedef       __attribute__((address_space(3))) unsigned int luint;

// ---------------- init: zero accumulators + convert W to bf16 ----------------
__global__ void k_init(const float* __restrict__ conv_w, float* __restrict__ ws,
                       float* __restrict__ out) {
    const int bx = blockIdx.x, tid = threadIdx.x;
    if (bx < 96) {
        __bf16* Wb = (__bf16*)(ws + WS_WBF);
        #pragma unroll
        for (int j = 0; j < 4; j++) {
            int idx = bx * 1024 + j * 256 + tid;
            Wb[idx] = (__bf16)conv_w[idx];
        }
    } else {
        for (int k = tid; k < 2048; k += 256) ws[k] = 0.f;
        if (tid < 2) out[tid] = 0.f;
    }
}

// ---------------- bilinear sample of t_logit row (65x65 -> 129x129) ----------------
__device__ __forceinline__ float t_resized(const float* __restrict__ Trow, int k) {
    int y = k / 129, x = k - y * 129;
    int y0 = y >> 1, x0 = x >> 1;
    int y1 = y0 + (y & 1), x1 = x0 + (x & 1);
    float fy = 0.5f * (float)(y & 1), fx = 0.5f * (float)(x & 1);
    float v00 = Trow[y0 * 65 + x0], v01 = Trow[y0 * 65 + x1];
    float v10 = Trow[y1 * 65 + x0], v11 = Trow[y1 * 65 + x1];
    float r0 = v00 + fx * (v01 - v00);
    float r1 = v10 + fx * (v11 - v10);
    return r0 + fy * (r1 - r0);
}

// ---------------- main: rowstats (0..303) + pi (304..2415) + corner px (2416..2423) --
// PROVEN round-2 build (81.3 us): pi block = (b, strip of 64 px, ch-quarter of 192).
// t_out: 3 chunks, ALL issued before first use; raw s_barrier + lgkmcnt keeps
// prefetch in flight; waits vmcnt(8)/(4)/(0).
__launch_bounds__(256, 3)
__global__ void k_main(const float* __restrict__ s_out, const float* __restrict__ t_out,
                       const float* __restrict__ conv_w, const float* __restrict__ bias,
                       const float* __restrict__ s_logit, const float* __restrict__ t_logit,
                       float* __restrict__ ws, float* __restrict__ out) {
    __shared__ __align__(16) char lds[50176];
    const int tid = threadIdx.x;
    const int bx  = blockIdx.x;

    if (bx >= 304 && bx < 2416) {
        // ================= pi role =================
        const int idx     = bx - 304;
        const int quarter = idx & 3;
        const int bs      = idx >> 2;
        const int b       = bs / 66;
        const int strip   = bs - b * 66;
        const int px0     = strip * 64;

        const int l = tid & 63, g = tid >> 6, q = l >> 4, n = l & 15;
        const int og = quarter * 192 + g * 16;

        const float* base_t = t_out + (size_t)(b * 768 + og) * 4225;
        int off[4];
        #pragma unroll
        for (int j = 0; j < 4; j++) {
            int col = ((n * 4) + j * 16) & 63;
            off[j] = (j * 4 + q) * 4225 + px0 + col;
        }
        int colr[4];
        #pragma unroll
        for (int pt = 0; pt < 4; pt++)
            colr[pt] = (((pt * 16 + (n & 12) - q * 16) & 63)) + (n & 3);

        auto issue_t = [&](int cc) {
            char* lb = (cc == 2) ? (lds + g * 4096) : (lds + 17408 + cc * 16384 + g * 4096);
            const float* gb = base_t + (size_t)cc * 64 * 4225;
            #pragma unroll
            for (int j = 0; j < 4; j++)
                __builtin_amdgcn_global_load_lds((guint*)(gb + off[j]),
                                                 (luint*)(lb + j * 1024), 16, 0, 0);
        };

        issue_t(0);
        issue_t(1);

        __bf16* xs = (__bf16*)lds;               // 64 px x 136 c bf16

        {
            const float* Sb = s_out + b * 128 * 1089;
            #pragma unroll
            for (int ii = 0; ii < 32; ii++) {
                int id2 = tid + ii * 256;
                int c = id2 >> 6, px = id2 & 63;
                int hw = px0 + px;
                int h = hw / 65, w = hw - h * 65;
                int y0 = h >> 1, x0 = w >> 1;
                int y1 = y0 + (h & 1), x1 = x0 + (w & 1);
                float wy = 0.5f * (float)(h & 1), wx = 0.5f * (float)(w & 1);
                const float* Sc = Sb + c * 1089;
                float v00 = Sc[y0 * 33 + x0], v01 = Sc[y0 * 33 + x1];
                float v10 = Sc[y1 * 33 + x0], v11 = Sc[y1 * 33 + x1];
                float r0 = v00 + wx * (v01 - v00);
                float r1 = v10 + wx * (v11 - v10);
                xs[px * 136 + c] = (__bf16)(r0 + wy * (r1 - r0));
            }
        }
        asm volatile("s_waitcnt lgkmcnt(0)" ::: "memory");
        __builtin_amdgcn_s_barrier();
        __builtin_amdgcn_sched_barrier(0);

        bf16x8 bfrag[4][4];
        #pragma unroll
        for (int pt = 0; pt < 4; pt++)
            #pragma unroll
            for (int kf = 0; kf < 4; kf++)
                bfrag[pt][kf] = *(const bf16x8*)&xs[(pt * 16 + n) * 136 + kf * 32 + q * 8];

        const __bf16* Wbf = (const __bf16*)(ws + WS_WBF);
        bf16x8 afr[3][4];
        f32x4  bq[3];
        auto load_a = [&](int cc) {
            const __bf16* Wr = Wbf + (size_t)(og + cc * 64 + n) * 128 + q * 8;
            #pragma unroll
            for (int kf = 0; kf < 4; kf++) afr[cc][kf] = *(const bf16x8*)(Wr + kf * 32);
            bq[cc] = *(const f32x4*)&bias[og + cc * 64 + q * 4];
        };
        load_a(0);
        load_a(1);

        asm volatile("s_waitcnt lgkmcnt(0)" ::: "memory");
        __builtin_amdgcn_s_barrier();
        __builtin_amdgcn_sched_barrier(0);
        issue_t(2);

        float Zt[4], St[4], Dd[4], Zs[4];
        #pragma unroll
        for (int pt = 0; pt < 4; pt++) { Zt[pt] = 0.f; St[pt] = 0.f; Dd[pt] = 0.f; Zs[pt] = 0.f; }

        #pragma unroll
        for (int c = 0; c < 3; c++) {
            if (c == 0)      asm volatile("s_waitcnt vmcnt(8)" ::: "memory");
            else if (c == 1) asm volatile("s_waitcnt vmcnt(4)" ::: "memory");
            else             asm volatile("s_waitcnt vmcnt(0)" ::: "memory");
            if (c == 1) load_a(2);

            const float* tw = (const float*)((c == 2) ? (lds + g * 4096)
                                                      : (lds + 17408 + c * 16384 + g * 4096));
            #pragma unroll
            for (int pt = 0; pt < 4; pt++) {
                f32x4 a0 = {0.f, 0.f, 0.f, 0.f};
                #pragma unroll
                for (int kf = 0; kf < 4; kf++)
                    a0 = __builtin_amdgcn_mfma_f32_16x16x32_bf16(afr[c][kf], bfrag[pt][kf], a0, 0, 0, 0);
                #pragma unroll
                for (int r = 0; r < 4; r++) {
                    float tv  = tw[(q * 4 + r) * 64 + colr[pt]];
                    float s1v = a0[r] + bq[c][r];
                    float e   = __expf(tv);
                    Zt[pt] += e;
                    St[pt]  = fmaf(e, tv,  St[pt]);
                    Dd[pt]  = fmaf(e, s1v, Dd[pt]);
                    Zs[pt] += __expf(s1v);
                }
            }
        }

        __syncthreads();
        float* scr = (float*)lds;
        {
            int p = g * 4 + q;
            #pragma unroll
            for (int pt = 0; pt < 4; pt++) {
                f32x4 v = {Zt[pt], St[pt], Dd[pt], Zs[pt]};
                *(f32x4*)&scr[(pt * 16 + n) * 68 + p * 4] = v;
            }
        }
        __syncthreads();
        if (tid < 64) {
            float Z = 0.f, S = 0.f, D = 0.f, Z2 = 0.f;
            #pragma unroll
            for (int p = 0; p < 16; p++) {
                f32x4 v = *(const f32x4*)&scr[tid * 68 + p * 4];
                Z += v[0]; S += v[1]; D += v[2]; Z2 += v[3];
            }
            f32x4 o4 = {Z, S, D, Z2};
            *(f32x4*)&ws[WS_PART + (((size_t)quarter * 8 + b) * 4224 + px0 + tid) * 4] = o4;
        }
    } else if (bx < 304) {
        // ================= rowstats role =================
        float* red = (float*)lds;
        int row  = bx;
        int side = (row >= 152) ? 1 : 0;
        int r    = side ? row - 152 : row;
        const float* src = side ? (t_logit + r * 4225) : (s_logit + r * 16641);

        float z = 0.f, s = 0.f;
        #pragma unroll 4
        for (int k = tid; k < 16641; k += 256) {
            float v = side ? t_resized(src, k) : src[k];
            float e = __expf(v);
            z += e;
            s = fmaf(e, v, s);
        }
        for (int off = 32; off > 0; off >>= 1) { z += __shfl_down(z, off); s += __shfl_down(s, off); }
        if ((tid & 63) == 0) { red[tid >> 6] = z; red[4 + (tid >> 6)] = s; }
        __syncthreads();
        if (tid == 0) {
            float Z = red[0] + red[1] + red[2] + red[3];
            float S = red[4] + red[5] + red[6] + red[7];
            ws[WS_Z + row] = Z;
            atomicAdd(&ws[(side ? WS_E1 : WS_E0) + (r % 19)], S / Z - logf(Z));
        }
    } else {
        // ================= corner pixel (px 4224) role, one block per b ==========
        float* xc  = (float*)lds;          // 128
        float* red = (float*)lds + 128;    // 16
        const int b = bx - 2416;
        if (tid < 128) xc[tid] = s_out[((size_t)b * 128 + tid) * 1089 + 1088];
        __syncthreads();
        float z = 0.f, s = 0.f, d = 0.f, z2 = 0.f;
        #pragma unroll
        for (int rep = 0; rep < 3; rep++) {
            int o = tid + rep * 256;
            const float* Wr = conv_w + (size_t)o * 128;
            float s1 = bias[o];
            for (int cc = 0; cc < 128; cc++) s1 = fmaf(Wr[cc], xc[cc], s1);
            float tv = t_out[((size_t)(b * 768 + o)) * 4225 + 4224];
            float e  = __expf(tv);
            z += e; s = fmaf(e, tv, s); d = fmaf(e, s1, d); z2 += __expf(s1);
        }
        for (int off = 32; off > 0; off >>= 1) {
            z += __shfl_down(z, off); s += __shfl_down(s, off);
            d += __shfl_down(d, off); z2 += __shfl_down(z2, off);
        }
        if ((tid & 63) == 0) {
            int wv = tid >> 6;
            red[wv] = z; red[4 + wv] = s; red[8 + wv] = d; red[12 + wv] = z2;
        }
        __syncthreads();
        if (tid == 0) {
            float Z = red[0] + red[1] + red[2] + red[3];
            float S = red[4] + red[5] + red[6] + red[7];
            float D = red[8] + red[9] + red[10] + red[11];
            float Z2 = red[12] + red[13] + red[14] + red[15];
            float contrib = (S - D) / Z - logf(Z) + logf(Z2);
            atomicAdd(out, contrib * (1.0f / 25958400.0f));
        }
    }
}

// ---------------- mid: Gram (0..527, 512 threads) + pi finalize (528..593) ----------
// Phase 1: one element per thread (coalesced, 19 clean iterations).
// Phase 2: each of 190 pairs split across 2 threads (380/512 active), halves
// combined via shfl_xor -> serial dot length halved to 256.
#define KT 512
#define KP 516
__global__ __launch_bounds__(512)
void k_mid(const float* __restrict__ s_logit, const float* __restrict__ t_logit,
           float* __restrict__ ws, float* __restrict__ out) {
    __shared__ __align__(16) char lds[39296];
    const int tid = threadIdx.x;
    const int bx  = blockIdx.x;

    if (bx < 528) {
        float* pbuf  = (float*)lds;               // [19][516]
        float* rowiz = (float*)(lds + 39216);     // [19]
        int side = (bx >= 264) ? 1 : 0;
        int rm   = side ? bx - 264 : bx;
        int b = rm / 33, kt = rm - b * 33;
        int k0 = kt * KT;

        if (tid < 19) rowiz[tid] = 1.0f / ws[WS_Z + side * 152 + b * 19 + tid];
        __syncthreads();

        const int k   = k0 + tid;                 // tid < 512 = KT
        const bool inb = (k < 16641);
        #pragma unroll 1
        for (int i = 0; i < 19; i++) {
            const float* src = side ? (t_logit + (size_t)(b * 19 + i) * 4225)
                                    : (s_logit + (size_t)(b * 19 + i) * 16641);
            float p = 0.f;
            if (inb) {
                float v = side ? t_resized(src, k) : src[k];
                p = __expf(v) * rowiz[i];
            }
            pbuf[i * KP + tid] = p;
        }
        __syncthreads();

        if (tid < 380) {
            int pr = tid >> 1, h = tid & 1;
            int t = pr, i = 0;
            while (t >= 19 - i) { t -= 19 - i; i++; }
            int j = i + t;
            const float* pi_ = &pbuf[i * KP + h * 256];
            const float* pj_ = &pbuf[j * KP + h * 256];
            float g0 = 0.f, g1 = 0.f, g2 = 0.f, g3 = 0.f;
            #pragma unroll 2
            for (int kl = 0; kl < 256; kl += 16) {
                float4 a0 = *(const float4*)&pi_[kl];      float4 c0 = *(const float4*)&pj_[kl];
                float4 a1 = *(const float4*)&pi_[kl + 4];  float4 c1 = *(const float4*)&pj_[kl + 4];
                float4 a2 = *(const float4*)&pi_[kl + 8];  float4 c2 = *(const float4*)&pj_[kl + 8];
                float4 a3 = *(const float4*)&pi_[kl + 12]; float4 c3 = *(const float4*)&pj_[kl + 12];
                g0 = fmaf(a0.x, c0.x, g0); g0 = fmaf(a0.y, c0.y, g0);
                g0 = fmaf(a0.z, c0.z, g0); g0 = fmaf(a0.w, c0.w, g0);
                g1 = fmaf(a1.x, c1.x, g1); g1 = fmaf(a1.y, c1.y, g1);
                g1 = fmaf(a1.z, c1.z, g1); g1 = fmaf(a1.w, c1.w, g1);
                g2 = fmaf(a2.x, c2.x, g2); g2 = fmaf(a2.y, c2.y, g2);
                g2 = fmaf(a2.z, c2.z, g2); g2 = fmaf(a2.w, c2.w, g2);
                g3 = fmaf(a3.x, c3.x, g3); g3 = fmaf(a3.y, c3.y, g3);
                g3 = fmaf(a3.z, c3.z, g3); g3 = fmaf(a3.w, c3.w, g3);
            }
            float g = (g0 + g1) + (g2 + g3);
            g += __shfl_xor(g, 1);                // combine the two halves
            if (h == 0)
                atomicAdd(&ws[(side ? WS_G1 : WS_G0) + i * 19 + j], g);
        }
    } else {
        // pi finalize: 66 blocks x 512 threads = 33792 = 8 b x 4224 px
        float* red = (float*)lds;
        int gp = (bx - 528) * 512 + tid;
        int b  = gp / 4224;
        int tp = gp - b * 4224;
        float Z = 0.f, S = 0.f, D = 0.f, Z2 = 0.f;
        #pragma unroll
        for (int qq = 0; qq < 4; qq++) {
            f32x4 v = *(const f32x4*)&ws[WS_PART + (((size_t)qq * 8 + b) * 4224 + tp) * 4];
            Z += v[0]; S += v[1]; D += v[2]; Z2 += v[3];
        }
        float contrib = (S - D) / Z - logf(Z) + logf(Z2);
        for (int off = 32; off > 0; off >>= 1) contrib += __shfl_down(contrib, off);
        if ((tid & 63) == 0) red[tid >> 6] = contrib;
        __syncthreads();
        if (tid == 0) {
            float tot = 0.f;
            #pragma unroll
            for (int w = 0; w < 8; w++) tot += red[w];
            atomicAdd(out, tot * (1.0f / 25958400.0f));
        }
    }
}

// ---------------- finalize lo_loss (1 block, 384 threads) ----------------
__global__ void k_final(const float* __restrict__ ws, float* __restrict__ out) {
    __shared__ float Ms[361], Mt[361], ns[19], nt[19];
    __shared__ float red[8];
    int tid = threadIdx.x;
    if (tid < 361) {
        int i = tid / 19, j = tid - i * 19;
        int lo = min(i, j), hi = max(i, j);
        Ms[tid] = (ws[WS_E0 + hi] - ws[WS_G0 + lo * 19 + hi]) * 0.125f;
        Mt[tid] = (ws[WS_E1 + hi] - ws[WS_G1 + lo * 19 + hi]) * 0.125f;
    }
    __syncthreads();
    if (tid < 19) {
        float as = 0.f, at = 0.f;
        for (int j = 0; j < 19; j++) {
            as = fmaf(Ms[tid * 19 + j], Ms[tid * 19 + j], as);
            at = fmaf(Mt[tid * 19 + j], Mt[tid * 19 + j], at);
        }
        ns[tid] = fmaxf(sqrtf(as), 1e-12f);
        nt[tid] = fmaxf(sqrtf(at), 1e-12f);
    }
    __syncthreads();
    float d = 0.f;
    if (tid < 361) {
        int i = tid / 19;
        float v = Ms[tid] / ns[i] - Mt[tid] / nt[i];
        d = v * v;
    }
    for (int off = 32; off > 0; off >>= 1) d += __shfl_down(d, off);
    if ((tid & 63) == 0) red[tid >> 6] = d;
    __syncthreads();
    if (tid == 0) out[1] = red[0] + red[1] + red[2] + red[3] + red[4] + red[5];
}

extern "C" void kernel_launch(void* const* d_in, const int* in_sizes, int n_in,
                              void* d_out, int out_size, void* d_ws, size_t ws_size,
                              hipStream_t stream) {
    const float* s_out   = (const float*)d_in[0];
    const float* t_out   = (const float*)d_in[1];
    const float* t_logit = (const float*)d_in[2];
    const float* s_logit = (const float*)d_in[3];
    const float* conv_w  = (const float*)d_in[4];
    const float* conv_b  = (const float*)d_in[5];
    float* out = (float*)d_out;
    float* ws  = (float*)d_ws;

    k_init<<<dim3(97), dim3(256), 0, stream>>>(conv_w, ws, out);
    k_main<<<dim3(2424), dim3(256), 0, stream>>>(s_out, t_out, conv_w, conv_b,
                                                 s_logit, t_logit, ws, out);
    k_mid<<<dim3(594), dim3(512), 0, stream>>>(s_logit, t_logit, ws, out);
    k_final<<<dim3(1), dim3(384), 0, stream>>>(ws, out);
}